// Round 2
// baseline (38621.774 us; speedup 1.0000x reference)
//
#include <hip/hip_runtime.h>
#include <hip/hip_bf16.h>

#define Bdim 256
#define Sdim 512
#define Cdim 512
#define Hdim 512

typedef __attribute__((ext_vector_type(8))) short bfrag;     // 8 bf16 MFMA A/B frag
typedef __attribute__((ext_vector_type(8))) unsigned short u16x8;
typedef __attribute__((ext_vector_type(4))) float f32x4;     // MFMA C/D frag

__device__ __forceinline__ unsigned short f2bf_rne(float f) {
    union { float f; unsigned u; } v; v.f = f;
    return (unsigned short)((v.u + 0x7fffu + ((v.u >> 16) & 1u)) >> 16);
}
__device__ __forceinline__ float sigmoidf_(float x) { return 1.0f / (1.0f + __expf(-x)); }

// ---------------------------------------------------------------------------
// Pack a K x N fp32 weight (row-major, B[k][n]=src[k*N+n]) into bf16 MFMA
// B-fragment layout: dst[(n16*(K/32)+kc)*512 + lane*8 + j] = B[kc*32+(lane>>4)*8+j][n16*16+(lane&15)]
// Used for Q (512x512) and R (512x512); K==512.
__global__ __launch_bounds__(256) void pack_weight(const float* __restrict__ src,
                                                   unsigned short* __restrict__ dst) {
    int tid = blockIdx.x * 256 + threadIdx.x;
    int lane = tid & 63;
    int blk  = tid >> 6;
    int kc   = blk & 15;
    int n16  = blk >> 4;
    int n  = (n16 << 4) + (lane & 15);
    int kb = (kc << 5) + ((lane >> 4) << 3);
    u16x8 v;
#pragma unroll
    for (int j = 0; j < 8; ++j) v[j] = f2bf_rne(src[(size_t)(kb + j) * 512 + n]);
    *(u16x8*)(dst + ((size_t)tid << 3)) = v;
}

// ---------------------------------------------------------------------------
// Build fused gates weight Wcat (K=1024, Ncols=2048 permuted) in packed B-frag
// layout, fp32 accumulate:
//   k<512  (x-path): W[k][o] = Wih[o][k] + sum_j Wmx[j][k]*Whm[o][j]
//   k>=512 (h-path): W[k][o] = sum_j Wmh[j][k-512]*Whm[o][j]
// Column permutation: source o = gi*512+n  ->  packed col c' = (n>>5)*128 + gi*32 + (n&31)
// so each WG (n-slice) owns all 4 gates, and wave wv owns gate wv.
__global__ __launch_bounds__(256) void build_wcat(const float* __restrict__ Wmx,
                                                  const float* __restrict__ Wmh,
                                                  const float* __restrict__ Whm,
                                                  const float* __restrict__ Wih,
                                                  unsigned short* __restrict__ packW) {
    __shared__ float As[16][17], Bs[16][17];
    int kk0 = blockIdx.x * 16, o0 = blockIdx.y * 16;
    int tl = threadIdx.x & 15, th = threadIdx.x >> 4;
    int kk = kk0 + th;
    float acc = 0.f;
    for (int j0 = 0; j0 < 512; j0 += 16) {
        As[th][tl] = (kk < 512) ? Wmx[(size_t)(j0 + tl) * 512 + kk]
                                : Wmh[(size_t)(j0 + tl) * 512 + (kk - 512)];
        Bs[th][tl] = Whm[(size_t)(o0 + th) * 512 + j0 + tl];
        __syncthreads();
#pragma unroll
        for (int j = 0; j < 16; ++j) acc += As[th][j] * Bs[tl][j];
        __syncthreads();
    }
    int o = o0 + tl;
    if (kk < 512) acc += Wih[(size_t)o * 512 + kk];
    int gi = o >> 9, n = o & 511;
    int cp = (n >> 5) * 128 + gi * 32 + (n & 31);
    int n16 = cp >> 4, kc = kk >> 5, r = kk & 31;
    int lane = ((r >> 3) << 4) | (cp & 15), j = r & 7;
    packW[((size_t)(n16 * 32 + kc) << 9) + lane * 8 + j] = f2bf_rne(acc);
}

// b'[o] = sum_j (Wmx_b[j]+Wmh_b[j])*Whm[o][j] + Wih_b[o] + Whm_b[o]
__global__ __launch_bounds__(256) void build_bias(const float* __restrict__ Wmx_b,
                                                  const float* __restrict__ Wmh_b,
                                                  const float* __restrict__ Whm,
                                                  const float* __restrict__ Wih_b,
                                                  const float* __restrict__ Whm_b,
                                                  float* __restrict__ bprime) {
    int o = blockIdx.x * 256 + threadIdx.x;
    if (o >= 2048) return;
    float s = 0.f;
    for (int j = 0; j < 512; ++j) s += (Wmx_b[j] + Wmh_b[j]) * Whm[(size_t)o * 512 + j];
    bprime[o] = s + Wih_b[o] + Whm_b[o];
}

__global__ __launch_bounds__(256) void init_state(float* hm, float* cm,
                                                  unsigned short* axh, unsigned* bars) {
    int tid = blockIdx.x * 256 + threadIdx.x;
    if (tid < Bdim * Hdim) {
        hm[tid] = 0.f; cm[tid] = 0.f;
        int m = tid >> 9, n = tid & 511;
        axh[(size_t)m * 1024 + 512 + n] = 0;   // h-part of buffer 0
    }
    if (tid < 8 * 64) bars[tid] = 0;
}

// ---------------------------------------------------------------------------
// Persistent kernel: 8 row-groups x 32 rows; 16 WGs/group (grid=128, block=256).
// Phases/step: mog-x, mog-h, mog-x, mog-h, mog-x, gates(+cell). Group-scope
// monotone-counter barriers between phases.
__global__ __launch_bounds__(256, 2)
void moglstm_persist(const float* __restrict__ xin,
                     const unsigned short* __restrict__ packQ,
                     const unsigned short* __restrict__ packR,
                     const unsigned short* __restrict__ packW,
                     const float* __restrict__ bprime,
                     unsigned short* __restrict__ axh,   // 2 buffers of 256x1024 bf16
                     float* __restrict__ xm, float* __restrict__ hm,
                     float* __restrict__ cm,
                     unsigned* __restrict__ bars,
                     float* __restrict__ out) {
    __shared__ float gacc[4 * 32 * 33];
    const int wg  = blockIdx.x;
    const int grp = wg >> 4, wgi = wg & 15;
    const int tid  = threadIdx.x;
    const int lane = tid & 63, wv = tid >> 6;
    const int lm = lane & 15, lq = lane >> 4;
    const int mb = grp * 32;
    volatile unsigned* cnt = bars + grp * 64;
    unsigned nbar = 0;

    auto barrier = [&]() {
        __syncthreads();
        if (tid == 0) {
            __threadfence();
            atomicAdd((unsigned*)cnt, 1u);
            ++nbar;
            unsigned target = nbar * 16u;
            while (*cnt < target) __builtin_amdgcn_s_sleep(2);
            __threadfence();
        }
        __syncthreads();
    };

    // One mogrifier phase: dst[m][n] = 2*sigmoid((A_bf @ Wp)[m][n]) * prev[m][n]
    auto mog = [&](unsigned short* buf, int apart, const unsigned short* pack,
                   const float* prev, size_t prevStride, int dpart, float* dstf) {
        const int rh = wv & 1, ch = wv >> 1;
        const int arow = mb + rh * 16 + lm;
        const bfrag* A = (const bfrag*)(buf + (size_t)arow * 1024 + apart);
        const unsigned short* Bbase = pack + ((size_t)(wgi * 2 + ch) << 13);
        f32x4 acc = {};
#pragma unroll 4
        for (int kc = 0; kc < 16; ++kc) {
            bfrag a = A[kc * 4 + lq];
            bfrag b = *((const bfrag*)(Bbase + ((size_t)kc << 9)) + lane);
            acc = __builtin_amdgcn_mfma_f32_16x16x32_bf16(a, b, acc, 0, 0, 0);
        }
        const int n = wgi * 32 + ch * 16 + lm;
#pragma unroll
        for (int r = 0; r < 4; ++r) {
            int m = mb + rh * 16 + lq * 4 + r;
            float v = 2.f * sigmoidf_(acc[r]) * prev[(size_t)m * prevStride + n];
            dstf[(size_t)m * 512 + n] = v;
            buf[(size_t)m * 1024 + dpart + n] = f2bf_rne(v);
        }
    };

    for (int t = 0; t < Sdim; ++t) {
        unsigned short* cur = axh + (size_t)(t & 1) * (256 * 1024);
        unsigned short* nxt = axh + (size_t)((t + 1) & 1) * (256 * 1024);

        // p0: x = 2*sig(h@Q)*x_in   (reads h-part, writes x-part + xm)
        mog(cur, 512, packQ, xin + (size_t)t * 512, (size_t)Sdim * 512, 0, xm);
        barrier();
        // p1: h = 2*sig(x@R)*h
        mog(cur, 0, packR, hm, 512, 512, hm);
        barrier();
        // p2: x = 2*sig(h@Q)*x
        mog(cur, 512, packQ, xm, 512, 0, xm);
        barrier();
        // p3: h = 2*sig(x@R)*h
        mog(cur, 0, packR, hm, 512, 512, hm);
        barrier();
        // p4: x = 2*sig(h@Q)*x
        mog(cur, 512, packQ, xm, 512, 0, xm);
        barrier();

        // p5: gates = [x|h] @ Wcat + b', fused cell update. Wave wv owns gate wv.
        {
            const int n16b = wgi * 8 + wv * 2;
            f32x4 acc[2][2] = {};
            const bfrag* A0 = (const bfrag*)(cur + (size_t)(mb + lm) * 1024);
            const bfrag* A1 = (const bfrag*)(cur + (size_t)(mb + 16 + lm) * 1024);
#pragma unroll 2
            for (int kc = 0; kc < 32; ++kc) {
                bfrag a0 = A0[kc * 4 + lq], a1 = A1[kc * 4 + lq];
                bfrag b0 = *((const bfrag*)(packW + ((size_t)(n16b * 32 + kc) << 9)) + lane);
                bfrag b1 = *((const bfrag*)(packW + ((size_t)((n16b + 1) * 32 + kc) << 9)) + lane);
                acc[0][0] = __builtin_amdgcn_mfma_f32_16x16x32_bf16(a0, b0, acc[0][0], 0, 0, 0);
                acc[0][1] = __builtin_amdgcn_mfma_f32_16x16x32_bf16(a0, b1, acc[0][1], 0, 0, 0);
                acc[1][0] = __builtin_amdgcn_mfma_f32_16x16x32_bf16(a1, b0, acc[1][0], 0, 0, 0);
                acc[1][1] = __builtin_amdgcn_mfma_f32_16x16x32_bf16(a1, b1, acc[1][1], 0, 0, 0);
            }
#pragma unroll
            for (int mi = 0; mi < 2; ++mi)
#pragma unroll
            for (int ni = 0; ni < 2; ++ni) {
                int nn = ni * 16 + lm;
                float bias = bprime[wv * 512 + wgi * 32 + nn];
#pragma unroll
                for (int r = 0; r < 4; ++r) {
                    int mrow = mi * 16 + lq * 4 + r;
                    gacc[(wv * 32 + mrow) * 33 + nn] = acc[mi][ni][r] + bias;
                }
            }
            __syncthreads();
            // cell update: wave wv handles rows [wv*8, wv*8+8)
            int ncol = lane & 31, rb = lane >> 5;
#pragma unroll
            for (int rr = 0; rr < 4; ++rr) {
                int mrow = wv * 8 + rb * 4 + rr;
                float ig = gacc[(0 * 32 + mrow) * 33 + ncol];
                float fg = gacc[(1 * 32 + mrow) * 33 + ncol];
                float gg = gacc[(2 * 32 + mrow) * 33 + ncol];
                float og = gacc[(3 * 32 + mrow) * 33 + ncol];
                int m = mb + mrow, n = wgi * 32 + ncol;
                size_t idx = (size_t)m * 512 + n;
                float c = sigmoidf_(fg) * cm[idx] + sigmoidf_(ig) * tanhf(gg);
                cm[idx] = c;
                float h = sigmoidf_(og) * tanhf(c);
                hm[idx] = h;
                nxt[(size_t)m * 1024 + 512 + n] = f2bf_rne(h);  // h for next step
                out[((size_t)m * 512 + t) * 512 + n] = h;
            }
        }
        barrier();
    }
}

// ---------------------------------------------------------------------------
extern "C" void kernel_launch(void* const* d_in, const int* in_sizes, int n_in,
                              void* d_out, int out_size, void* d_ws, size_t ws_size,
                              hipStream_t stream) {
    const float* x     = (const float*)d_in[0];
    const float* Wih_w = (const float*)d_in[1];
    const float* Wih_b = (const float*)d_in[2];
    const float* Wmx_w = (const float*)d_in[3];
    const float* Wmx_b = (const float*)d_in[4];
    const float* Wmh_w = (const float*)d_in[5];
    const float* Wmh_b = (const float*)d_in[6];
    const float* Whm_w = (const float*)d_in[7];
    const float* Whm_b = (const float*)d_in[8];
    const float* Q     = (const float*)d_in[9];
    const float* R     = (const float*)d_in[10];
    float* out = (float*)d_out;

    // workspace layout (~7.6 MB)
    unsigned short* packQ = (unsigned short*)d_ws;
    unsigned short* packR = packQ + 512 * 512;
    unsigned short* packW = packR + 512 * 512;            // 1024 x 2048 packed
    float* bprime = (float*)(packW + 1024 * 2048);
    unsigned short* axh = (unsigned short*)(bprime + 2048);  // 2 x 256 x 1024 bf16
    float* xm = (float*)(axh + 2 * 256 * 1024);
    float* hm = xm + Bdim * Cdim;
    float* cm = hm + Bdim * Hdim;
    unsigned* bars = (unsigned*)(cm + Bdim * Hdim);       // 8 groups x 64 u32

    pack_weight<<<dim3(128), dim3(256), 0, stream>>>(Q, packQ);
    pack_weight<<<dim3(128), dim3(256), 0, stream>>>(R, packR);
    build_wcat<<<dim3(64, 128), dim3(256), 0, stream>>>(Wmx_w, Wmh_w, Whm_w, Wih_w, packW);
    build_bias<<<dim3(8), dim3(256), 0, stream>>>(Wmx_b, Wmh_b, Whm_w, Wih_b, Whm_b, bprime);
    init_state<<<dim3(512), dim3(256), 0, stream>>>(hm, cm, axh, bars);

    moglstm_persist<<<dim3(128), dim3(256), 0, stream>>>(
        x, packQ, packR, packW, bprime, axh, xm, hm, cm, bars, out);
}